// Round 8
// baseline (232.425 us; speedup 1.0000x reference)
//
#include <hip/hip_runtime.h>

// Adaptive downsampler: B=8, C=3, 1024x1024 -> 512x512, K2=9 taps,
// bilinear gather from reflect-padded (pad=1) image, weighted by kernels.
// R7 = R6 (best, 126.3us: 64x4 patch blocks, 27-wide nt preload, full
//      unroll, ld2 paired gathers, XCD slab swizzle, plain stores)
//      + __launch_bounds__(256,4): guarantee 4 blocks/CU packing
//      (16 waves/CU) to hide gather latency. Single-variable test.
constexpr int B_  = 8;
constexpr int C_  = 3;
constexpr int H_  = 1024;
constexpr int W_  = 1024;
constexpr int HO_ = 512;
constexpr int WO_ = 512;
constexpr int K2_ = 9;
constexpr int KS_ = 3;
constexpr int HP_ = H_ + 2;   // padded height (pad=1)
constexpr int WP_ = W_ + 2;   // padded width
constexpr int NBLK_ = (B_ * HO_ * WO_) / 256;   // 8192 blocks
constexpr int NXCD_ = 8;

__device__ __forceinline__ float2 ld2(const float* p) {
    float2 r;
    __builtin_memcpy(&r, p, sizeof(float2));   // global_load_dwordx2
    return r;
}

__global__ __launch_bounds__(256, 4) void ds_kernel(
    const float* __restrict__ img,
    const float* __restrict__ kern,
    const float* __restrict__ offh,
    const float* __restrict__ offv,
    const float* __restrict__ unit_p,
    float* __restrict__ out)
{
    const int HWo = HO_ * WO_;                       // 262144

    // XCD swizzle: block i runs on XCD i%8 (round-robin dispatch).
    // nid in [b*1024, b*1024+1023] = batch b -> XCD b owns one batch.
    const int wg  = blockIdx.x;
    const int nid = (wg & (NXCD_ - 1)) * (NBLK_ / NXCD_) + (wg >> 3);

    // 2D patch decode: nid = b*1024 + oyt*8 + oxt
    //   oyt 0..127 (quad of oy rows), oxt 0..7 (64-px ox chunk)
    // wave w of the block -> oy = oyt*4 + w; lanes -> ox = oxt*64 + lane.
    const int b   = nid >> 10;
    const int q   = nid & 1023;
    const int oyt = q >> 3;
    const int oxt = q & 7;
    const int wv  = threadIdx.x >> 6;
    const int ln  = threadIdx.x & 63;
    const int oy  = oyt * 4 + wv;
    const int ox  = oxt * 64 + ln;

    const float unit = unit_p[0];
    const float* imgb = img + (size_t)b * (C_ * H_ * W_);
    const int kbase = b * (K2_ * HWo) + oy * WO_ + ox;   // < 2^25

    // (ox+0.5)/WO*W - 0.5 == 2*ox + 0.5  (exact in fp32; W/WO = 2)
    const float cx = 2.0f * (float)ox + 0.5f;
    const float cy = 2.0f * (float)oy + 0.5f;

    // Phase 1: all 27 stream loads in flight (read-once -> nontemporal).
    float wk[K2_], oh[K2_], ov[K2_];
#pragma unroll
    for (int k = 0; k < K2_; ++k) {
        wk[k] = __builtin_nontemporal_load(kern + kbase + k * HWo);
        oh[k] = __builtin_nontemporal_load(offh + kbase + k * HWo);
        ov[k] = __builtin_nontemporal_load(offv + kbase + k * HWo);
    }

    float acc0 = 0.0f, acc1 = 0.0f, acc2 = 0.0f;

    // Phase 2: taps, fully unrolled (compile-time k -> regs, not scratch).
#pragma unroll
    for (int k = 0; k < K2_; ++k) {
        const float px = cx + (float)(k % KS_) + oh[k] * unit;
        const float py = cy + (float)(k / KS_) + ov[k] * unit;

        const float fx = floorf(px);
        const float fy = floorf(py);
        const float a  = px - fx;   // alpha
        const float bt = py - fy;   // beta

        // clip in PADDED coordinates [0, WP-1] / [0, HP-1]
        int xL = (int)fx; xL = xL < 0 ? 0 : (xL > WP_ - 1 ? WP_ - 1 : xL);
        int xR = xL + 1;  xR = xR > WP_ - 1 ? WP_ - 1 : xR;
        int yT = (int)fy; yT = yT < 0 ? 0 : (yT > HP_ - 1 ? HP_ - 1 : yT);
        int yB = yT + 1;  yB = yB > HP_ - 1 ? HP_ - 1 : yB;

        // padded -> original with reflect (pad=1): j=i-1; -1->1; H->H-2
        int xl = xL - 1; xl = (xl < 0) ? -xl : (xl >= W_ ? 2 * W_ - 2 - xl : xl);
        int xr = xR - 1; xr = (xr < 0) ? -xr : (xr >= W_ ? 2 * W_ - 2 - xr : xr);
        int yt = yT - 1; yt = (yt < 0) ? -yt : (yt >= H_ ? 2 * H_ - 2 - yt : yt);
        int yb = yB - 1; yb = (yb < 0) ? -yb : (yb >= H_ ? 2 * H_ - 2 - yb : yb);

        // |xl - xr| <= 1 always; base = min <= W-2, so [base,base+1] in-bounds.
        const int base = xl < xr ? xl : xr;
        const float ax0 = ((xl == base) ? (1.0f - a) : 0.0f)
                        + ((xr == base) ? a : 0.0f);
        const float ax1 = 1.0f - ax0;

        const float wt = wk[k] * (1.0f - bt);
        const float wb = wk[k] * bt;

        const int r0 = yt * W_ + base;
        const int r1 = yb * W_ + base;

        {
            const float2 v = ld2(imgb + r0);
            const float2 u = ld2(imgb + r1);
            acc0 = fmaf(wt, fmaf(ax0, v.x, ax1 * v.y),
                   fmaf(wb, fmaf(ax0, u.x, ax1 * u.y), acc0));
        }
        {
            const float2 v = ld2(imgb + H_ * W_ + r0);
            const float2 u = ld2(imgb + H_ * W_ + r1);
            acc1 = fmaf(wt, fmaf(ax0, v.x, ax1 * v.y),
                   fmaf(wb, fmaf(ax0, u.x, ax1 * u.y), acc1));
        }
        {
            const float2 v = ld2(imgb + 2 * H_ * W_ + r0);
            const float2 u = ld2(imgb + 2 * H_ * W_ + r1);
            acc2 = fmaf(wt, fmaf(ax0, v.x, ax1 * v.y),
                   fmaf(wb, fmaf(ax0, u.x, ax1 * u.y), acc2));
        }
    }

    const int obase = b * (C_ * HWo) + oy * WO_ + ox;
    out[obase]           = acc0;
    out[obase + HWo]     = acc1;
    out[obase + 2 * HWo] = acc2;
}

extern "C" void kernel_launch(void* const* d_in, const int* in_sizes, int n_in,
                              void* d_out, int out_size, void* d_ws, size_t ws_size,
                              hipStream_t stream) {
    const float* img  = (const float*)d_in[0];
    const float* kern = (const float*)d_in[1];
    const float* offh = (const float*)d_in[2];
    const float* offv = (const float*)d_in[3];
    const float* unit = (const float*)d_in[4];
    float* out = (float*)d_out;

    ds_kernel<<<NBLK_, 256, 0, stream>>>(img, kern, offh, offv, unit, out);
}

// Round 9
// 86.423 us; speedup vs baseline: 2.6894x; 2.6894x over previous
//
#include <hip/hip_runtime.h>

// Adaptive downsampler: B=8, C=3, 1024x1024 -> 512x512, K2=9 taps,
// bilinear gather from reflect-padded (pad=1) image, weighted by kernels.
// R8 = R6 (best 126.3us: 64x4 patch, 27-wide nt preload, XCD slab swizzle,
//      plain stores, NO launch_bounds cap — (256,4) caused VGPR spills)
//      + LDS window staging: 22x144x3ch (38KB) window loaded coalesced
//      (float4) once per block; taps read LDS instead of scattered global;
//      exact global-ld2 fallback for out-of-window outliers (exec-masked).
constexpr int B_  = 8;
constexpr int C_  = 3;
constexpr int H_  = 1024;
constexpr int W_  = 1024;
constexpr int HO_ = 512;
constexpr int WO_ = 512;
constexpr int K2_ = 9;
constexpr int KS_ = 3;
constexpr int HP_ = H_ + 2;   // padded height (pad=1)
constexpr int WP_ = W_ + 2;   // padded width
constexpr int NBLK_ = (B_ * HO_ * WO_) / 256;   // 8192 blocks
constexpr int NXCD_ = 8;

// LDS window: WY_ rows x WX_ cols x 3 channels
constexpr int WY_ = 22;
constexpr int WX_ = 144;
constexpr int WCH_ = WY_ * WX_;            // 3168 floats per channel
constexpr int NF4_ = 3 * WY_ * (WX_ / 4);  // 2376 float4 to stage

__device__ __forceinline__ float2 ld2(const float* p) {
    float2 r;
    __builtin_memcpy(&r, p, sizeof(float2));   // global_load_dwordx2
    return r;
}

__global__ __launch_bounds__(256) void ds_kernel(
    const float* __restrict__ img,
    const float* __restrict__ kern,
    const float* __restrict__ offh,
    const float* __restrict__ offv,
    const float* __restrict__ unit_p,
    float* __restrict__ out)
{
    const int HWo = HO_ * WO_;                       // 262144
    __shared__ float sh[3 * WCH_];                   // 38016 B

    // XCD swizzle: block i runs on XCD i%8; contiguous 1024-block slab
    // per XCD = one batch, oy-ordered -> image window L2-resident.
    const int wg  = blockIdx.x;
    const int nid = (wg & (NXCD_ - 1)) * (NBLK_ / NXCD_) + (wg >> 3);

    // 2D patch decode: nid = b*1024 + oyt*8 + oxt
    const int b   = nid >> 10;
    const int q   = nid & 1023;
    const int oyt = q >> 3;          // 0..127: quad of oy rows
    const int oxt = q & 7;           // 0..7:   64-px ox chunk
    const int wv  = threadIdx.x >> 6;
    const int ln  = threadIdx.x & 63;
    const int oy  = oyt * 4 + wv;
    const int ox  = oxt * 64 + ln;

    const float unit = unit_p[0];
    const float* imgb = img + (size_t)b * (C_ * H_ * W_);
    const int kbase = b * (K2_ * HWo) + oy * WO_ + ox;   // < 2^25

    // Window origin (orig-image coords), x 4-aligned for float4 staging.
    int wxlo = 2 * (oxt * 64) - 8;
    wxlo = wxlo < 0 ? 0 : (wxlo > W_ - WX_ ? W_ - WX_ : wxlo);   // 0..880, %4==0
    int wylo = 8 * oyt - 6;
    wylo = wylo < 0 ? 0 : (wylo > H_ - WY_ ? H_ - WY_ : wylo);   // 0..1002

    // Phase 1: all 27 stream loads in flight (read-once -> nontemporal).
    float wk[K2_], oh[K2_], ov[K2_];
#pragma unroll
    for (int k = 0; k < K2_; ++k) {
        wk[k] = __builtin_nontemporal_load(kern + kbase + k * HWo);
        oh[k] = __builtin_nontemporal_load(offh + kbase + k * HWo);
        ov[k] = __builtin_nontemporal_load(offv + kbase + k * HWo);
    }

    // Phase 2: stage the image window into LDS (coalesced float4).
    // it -> ch = it/792, row = (it%792)/36, c4 = it%36   (792 = 22*36)
#pragma unroll
    for (int i = 0; i < 10; ++i) {
        const int it = threadIdx.x + i * 256;
        if (it < NF4_) {
            const int ch  = it / (WY_ * (WX_ / 4));
            const int rem = it - ch * (WY_ * (WX_ / 4));
            const int row = rem / (WX_ / 4);
            const int c4  = rem - row * (WX_ / 4);
            const float4 v = ((const float4*)(imgb + ch * (H_ * W_)
                                + (wylo + row) * W_ + wxlo))[c4];
            ((float4*)(sh + ch * WCH_ + row * WX_))[c4] = v;
        }
    }
    __syncthreads();

    // (ox+0.5)/WO*W - 0.5 == 2*ox + 0.5  (exact in fp32; W/WO = 2)
    const float cx = 2.0f * (float)ox + 0.5f;
    const float cy = 2.0f * (float)oy + 0.5f;

    float acc0 = 0.0f, acc1 = 0.0f, acc2 = 0.0f;

    // Phase 3: taps, fully unrolled; LDS fast path + exact global fallback.
#pragma unroll
    for (int k = 0; k < K2_; ++k) {
        const float px = cx + (float)(k % KS_) + oh[k] * unit;
        const float py = cy + (float)(k / KS_) + ov[k] * unit;

        const float fx = floorf(px);
        const float fy = floorf(py);
        const float a  = px - fx;   // alpha
        const float bt = py - fy;   // beta

        // clip in PADDED coordinates [0, WP-1] / [0, HP-1]
        int xL = (int)fx; xL = xL < 0 ? 0 : (xL > WP_ - 1 ? WP_ - 1 : xL);
        int xR = xL + 1;  xR = xR > WP_ - 1 ? WP_ - 1 : xR;
        int yT = (int)fy; yT = yT < 0 ? 0 : (yT > HP_ - 1 ? HP_ - 1 : yT);
        int yB = yT + 1;  yB = yB > HP_ - 1 ? HP_ - 1 : yB;

        // padded -> original with reflect (pad=1): j=i-1; -1->1; H->H-2
        int xl = xL - 1; xl = (xl < 0) ? -xl : (xl >= W_ ? 2 * W_ - 2 - xl : xl);
        int xr = xR - 1; xr = (xr < 0) ? -xr : (xr >= W_ ? 2 * W_ - 2 - xr : xr);
        int yt = yT - 1; yt = (yt < 0) ? -yt : (yt >= H_ ? 2 * H_ - 2 - yt : yt);
        int yb = yB - 1; yb = (yb < 0) ? -yb : (yb >= H_ ? 2 * H_ - 2 - yb : yb);

        // |xl - xr| <= 1 always; base = min <= W-2, so [base,base+1] in-bounds.
        const int base = xl < xr ? xl : xr;
        const float ax0 = ((xl == base) ? (1.0f - a) : 0.0f)
                        + ((xr == base) ? a : 0.0f);
        const float ax1 = 1.0f - ax0;

        const float wt = wk[k] * (1.0f - bt);
        const float wb = wk[k] * bt;

        const int ymin = yt < yb ? yt : yb;
        const int ymax = yt < yb ? yb : yt;
        const bool inwin = (base >= wxlo) & (base <= wxlo + WX_ - 2)
                         & (ymin >= wylo) & (ymax <= wylo + WY_ - 1);

        if (inwin) {
            const int i_t = (yt - wylo) * WX_ + (base - wxlo);
            const int i_b = (yb - wylo) * WX_ + (base - wxlo);
            {
                const float* shc = sh;
                acc0 = fmaf(wt, fmaf(ax0, shc[i_t], ax1 * shc[i_t + 1]),
                       fmaf(wb, fmaf(ax0, shc[i_b], ax1 * shc[i_b + 1]), acc0));
            }
            {
                const float* shc = sh + WCH_;
                acc1 = fmaf(wt, fmaf(ax0, shc[i_t], ax1 * shc[i_t + 1]),
                       fmaf(wb, fmaf(ax0, shc[i_b], ax1 * shc[i_b + 1]), acc1));
            }
            {
                const float* shc = sh + 2 * WCH_;
                acc2 = fmaf(wt, fmaf(ax0, shc[i_t], ax1 * shc[i_t + 1]),
                       fmaf(wb, fmaf(ax0, shc[i_b], ax1 * shc[i_b + 1]), acc2));
            }
        } else {
            const int r0 = yt * W_ + base;
            const int r1 = yb * W_ + base;
            {
                const float2 v = ld2(imgb + r0);
                const float2 u = ld2(imgb + r1);
                acc0 = fmaf(wt, fmaf(ax0, v.x, ax1 * v.y),
                       fmaf(wb, fmaf(ax0, u.x, ax1 * u.y), acc0));
            }
            {
                const float2 v = ld2(imgb + H_ * W_ + r0);
                const float2 u = ld2(imgb + H_ * W_ + r1);
                acc1 = fmaf(wt, fmaf(ax0, v.x, ax1 * v.y),
                       fmaf(wb, fmaf(ax0, u.x, ax1 * u.y), acc1));
            }
            {
                const float2 v = ld2(imgb + 2 * H_ * W_ + r0);
                const float2 u = ld2(imgb + 2 * H_ * W_ + r1);
                acc2 = fmaf(wt, fmaf(ax0, v.x, ax1 * v.y),
                       fmaf(wb, fmaf(ax0, u.x, ax1 * u.y), acc2));
            }
        }
    }

    const int obase = b * (C_ * HWo) + oy * WO_ + ox;
    out[obase]           = acc0;
    out[obase + HWo]     = acc1;
    out[obase + 2 * HWo] = acc2;
}

extern "C" void kernel_launch(void* const* d_in, const int* in_sizes, int n_in,
                              void* d_out, int out_size, void* d_ws, size_t ws_size,
                              hipStream_t stream) {
    const float* img  = (const float*)d_in[0];
    const float* kern = (const float*)d_in[1];
    const float* offh = (const float*)d_in[2];
    const float* offv = (const float*)d_in[3];
    const float* unit = (const float*)d_in[4];
    float* out = (float*)d_out;

    ds_kernel<<<NBLK_, 256, 0, stream>>>(img, kern, offh, offv, unit, out);
}

// Round 10
// 71.975 us; speedup vs baseline: 3.2292x; 1.2007x over previous
//
#include <hip/hip_runtime.h>

// Adaptive downsampler: B=8, C=3, 1024x1024 -> 512x512, K2=9 taps,
// bilinear gather from reflect-padded (pad=1) image, weighted by kernels.
// R9 = R8 (86.4us: LDS window staging, 27-wide nt preload, XCD slab swizzle)
//      + 512-thr blocks / 64x8 patch / 30x144 window (24 waves/CU cap vs 16)
//      + fast-path VALU trim: in-window => no clip, reflect=identity, so
//        fast path skips clip/reflect/flip entirely (exact; fallback keeps
//        the full reference semantics for out-of-window taps).
constexpr int B_  = 8;
constexpr int C_  = 3;
constexpr int H_  = 1024;
constexpr int W_  = 1024;
constexpr int HO_ = 512;
constexpr int WO_ = 512;
constexpr int K2_ = 9;
constexpr int KS_ = 3;
constexpr int HP_ = H_ + 2;   // padded height (pad=1)
constexpr int WP_ = W_ + 2;   // padded width
constexpr int NBLK_ = (B_ * HO_ * WO_) / 512;   // 4096 blocks
constexpr int NXCD_ = 8;

// LDS window: WY_ rows x WX_ cols x 3 channels
constexpr int WY_  = 30;
constexpr int WX_  = 144;
constexpr int WX4_ = WX_ / 4;              // 36
constexpr int WCH_ = WY_ * WX_;            // 4320 floats per channel
constexpr int NF4_ = 3 * WY_ * WX4_;       // 3240 float4 to stage

__device__ __forceinline__ float2 ld2(const float* p) {
    float2 r;
    __builtin_memcpy(&r, p, sizeof(float2));   // global_load_dwordx2
    return r;
}

__global__ __launch_bounds__(512) void ds_kernel(
    const float* __restrict__ img,
    const float* __restrict__ kern,
    const float* __restrict__ offh,
    const float* __restrict__ offv,
    const float* __restrict__ unit_p,
    float* __restrict__ out)
{
    const int HWo = HO_ * WO_;                       // 262144
    __shared__ float sh[3 * WCH_];                   // 51840 B

    // XCD swizzle: block i runs on XCD i%8; contiguous 512-block slab
    // per XCD = one batch, oy-ordered -> image window L2-resident.
    const int wg  = blockIdx.x;
    const int nid = (wg & (NXCD_ - 1)) * (NBLK_ / NXCD_) + (wg >> 3);

    // 2D patch decode: nid = b*512 + oyt*8 + oxt
    const int b   = nid >> 9;
    const int q   = nid & 511;
    const int oyt = q >> 3;          // 0..63: 8-row oy group
    const int oxt = q & 7;           // 0..7:  64-px ox chunk
    const int wv  = threadIdx.x >> 6;   // 0..7
    const int ln  = threadIdx.x & 63;
    const int oy  = oyt * 8 + wv;
    const int ox  = oxt * 64 + ln;

    const float unit = unit_p[0];
    const float* imgb = img + (size_t)b * (C_ * H_ * W_);
    const int kbase = b * (K2_ * HWo) + oy * WO_ + ox;   // < 2^25

    // Window origin (orig-image coords), x 4-aligned for float4 staging.
    int wxlo = 128 * oxt - 8;
    wxlo = wxlo < 0 ? 0 : (wxlo > W_ - WX_ ? W_ - WX_ : wxlo);   // 0..880, %4==0
    int wylo = 16 * oyt - 7;
    wylo = wylo < 0 ? 0 : (wylo > H_ - WY_ ? H_ - WY_ : wylo);   // 0..994

    // Phase 1: all 27 stream loads in flight (read-once -> nontemporal).
    float wk[K2_], oh[K2_], ov[K2_];
#pragma unroll
    for (int k = 0; k < K2_; ++k) {
        wk[k] = __builtin_nontemporal_load(kern + kbase + k * HWo);
        oh[k] = __builtin_nontemporal_load(offh + kbase + k * HWo);
        ov[k] = __builtin_nontemporal_load(offv + kbase + k * HWo);
    }

    // Phase 2: stage the image window into LDS (coalesced float4).
#pragma unroll
    for (int i = 0; i < 7; ++i) {
        const int it = threadIdx.x + i * 512;
        if (it < NF4_) {
            const int ch  = it / (WY_ * WX4_);
            const int rem = it - ch * (WY_ * WX4_);
            const int row = rem / WX4_;
            const int c4  = rem - row * WX4_;
            const float4 v = ((const float4*)(imgb + ch * (H_ * W_)
                                + (wylo + row) * W_ + wxlo))[c4];
            ((float4*)(sh + ch * WCH_ + row * WX_))[c4] = v;
        }
    }
    __syncthreads();

    // (ox+0.5)/WO*W - 0.5 == 2*ox + 0.5  (exact in fp32; W/WO = 2)
    const float cx = 2.0f * (float)ox + 0.5f;
    const float cy = 2.0f * (float)oy + 0.5f;

    float acc0 = 0.0f, acc1 = 0.0f, acc2 = 0.0f;

    // Phase 3: taps, fully unrolled; lean LDS fast path + exact fallback.
#pragma unroll
    for (int k = 0; k < K2_; ++k) {
        const float px = cx + (float)(k % KS_) + oh[k] * unit;
        const float py = cy + (float)(k / KS_) + ov[k] * unit;

        const float fx = floorf(px);
        const float fy = floorf(py);
        const float a  = px - fx;   // alpha
        const float bt = py - fy;   // beta

        // raw corner (orig coords); if in window, clip is inactive and
        // reflect is identity (window subset of [0,W-1]x[0,H-1]).
        const int x0 = (int)fx - 1;
        const int y0 = (int)fy - 1;

        const float wt = wk[k] * (1.0f - bt);
        const float wb = wk[k] * bt;

        const bool inwin = (x0 >= wxlo) & (x0 <= wxlo + WX_ - 2)
                         & (y0 >= wylo) & (y0 <= wylo + WY_ - 2);

        if (inwin) {
            const float ax0 = 1.0f - a;
            const float ax1 = a;
            const int i_t = (y0 - wylo) * WX_ + (x0 - wxlo);
            const int i_b = i_t + WX_;
            {
                const float* shc = sh;
                acc0 = fmaf(wt, fmaf(ax0, shc[i_t], ax1 * shc[i_t + 1]),
                       fmaf(wb, fmaf(ax0, shc[i_b], ax1 * shc[i_b + 1]), acc0));
            }
            {
                const float* shc = sh + WCH_;
                acc1 = fmaf(wt, fmaf(ax0, shc[i_t], ax1 * shc[i_t + 1]),
                       fmaf(wb, fmaf(ax0, shc[i_b], ax1 * shc[i_b + 1]), acc1));
            }
            {
                const float* shc = sh + 2 * WCH_;
                acc2 = fmaf(wt, fmaf(ax0, shc[i_t], ax1 * shc[i_t + 1]),
                       fmaf(wb, fmaf(ax0, shc[i_b], ax1 * shc[i_b + 1]), acc2));
            }
        } else {
            // exact reference semantics: clip in padded coords + reflect
            int xL = (int)fx; xL = xL < 0 ? 0 : (xL > WP_ - 1 ? WP_ - 1 : xL);
            int xR = xL + 1;  xR = xR > WP_ - 1 ? WP_ - 1 : xR;
            int yT = (int)fy; yT = yT < 0 ? 0 : (yT > HP_ - 1 ? HP_ - 1 : yT);
            int yB = yT + 1;  yB = yB > HP_ - 1 ? HP_ - 1 : yB;

            int xl = xL - 1; xl = (xl < 0) ? -xl : (xl >= W_ ? 2 * W_ - 2 - xl : xl);
            int xr = xR - 1; xr = (xr < 0) ? -xr : (xr >= W_ ? 2 * W_ - 2 - xr : xr);
            int yt = yT - 1; yt = (yt < 0) ? -yt : (yt >= H_ ? 2 * H_ - 2 - yt : yt);
            int yb = yB - 1; yb = (yb < 0) ? -yb : (yb >= H_ ? 2 * H_ - 2 - yb : yb);

            const int base = xl < xr ? xl : xr;
            const float ax0 = ((xl == base) ? (1.0f - a) : 0.0f)
                            + ((xr == base) ? a : 0.0f);
            const float ax1 = 1.0f - ax0;

            const int r0 = yt * W_ + base;
            const int r1 = yb * W_ + base;
            {
                const float2 v = ld2(imgb + r0);
                const float2 u = ld2(imgb + r1);
                acc0 = fmaf(wt, fmaf(ax0, v.x, ax1 * v.y),
                       fmaf(wb, fmaf(ax0, u.x, ax1 * u.y), acc0));
            }
            {
                const float2 v = ld2(imgb + H_ * W_ + r0);
                const float2 u = ld2(imgb + H_ * W_ + r1);
                acc1 = fmaf(wt, fmaf(ax0, v.x, ax1 * v.y),
                       fmaf(wb, fmaf(ax0, u.x, ax1 * u.y), acc1));
            }
            {
                const float2 v = ld2(imgb + 2 * H_ * W_ + r0);
                const float2 u = ld2(imgb + 2 * H_ * W_ + r1);
                acc2 = fmaf(wt, fmaf(ax0, v.x, ax1 * v.y),
                       fmaf(wb, fmaf(ax0, u.x, ax1 * u.y), acc2));
            }
        }
    }

    const int obase = b * (C_ * HWo) + oy * WO_ + ox;
    out[obase]           = acc0;
    out[obase + HWo]     = acc1;
    out[obase + 2 * HWo] = acc2;
}

extern "C" void kernel_launch(void* const* d_in, const int* in_sizes, int n_in,
                              void* d_out, int out_size, void* d_ws, size_t ws_size,
                              hipStream_t stream) {
    const float* img  = (const float*)d_in[0];
    const float* kern = (const float*)d_in[1];
    const float* offh = (const float*)d_in[2];
    const float* offv = (const float*)d_in[3];
    const float* unit = (const float*)d_in[4];
    float* out = (float*)d_out;

    ds_kernel<<<NBLK_, 512, 0, stream>>>(img, kern, offh, offv, unit, out);
}